// Round 8
// baseline (145.196 us; speedup 1.0000x reference)
//
#include <hip/hip_runtime.h>
#include <hip/hip_bf16.h>

// SupConLoss, B=8192, D=128, T=0.1. Output: single fp32 scalar.
//
// Pipeline (memset + 4 launches):
//   0) hipMemsetAsync  — zeroes 16 class-sum replicas + final accumulators.
//   1) supcon_convert  — dtype detection; features -> bf16 ws copy (RTNE),
//      labels -> int32; class sums accumulated into 16 REPLICAS of g
//      (rep = blockIdx&15) -> same-address atomic depth 82 -> ~5
//      (r7 lesson: single-copy g = 1M atomics on 12.8K addrs = ~23us of
//      coherence-point serialization).
//   2) supcon_gmerge   — folds 16 replicas into g[0] (50 blocks, ~3us).
//   3) supcon_main     — fused bf16-MFMA GEMM (F.F^T) + exp accumulation.
//      T4 counted-vmcnt pipeline: raw s_barrier + asm vmcnt(4) waits only
//      for the PREVIOUS tile's stage (issued a full iteration ago ~= free);
//      the just-issued stage stays in flight across the barrier (never
//      drain to 0 in-loop). Was: __syncthreads -> vmcnt(0) drain of the
//      just-issued stage every iteration = m233 structural stall, the
//      reason main sat at ~35us through three restructures.
//   4) supcon_reduce   — e partials + p_i = a_i.g[lab_i] dot -> loss.
//      n_i from exact label histogram. Diagonal removed exactly.
//      Last-block-atomic finalization (ticket zeroed by memset).
//
// Math: with ANY fixed shift M, per row i:
//   mean_log_prob_i = 10*p_i/n_i - M - log(sum_{j!=i} exp(s_ij - M))
// (shift cancels; M=10.5 >= max s_ij for unit-norm). exp folded to exp2.
//
// History:
//  r1: launch_bounds(256,4) -> VGPR=64 spill, 46->215us. Never clamp.
//  r2: NC=16 + n_acc removal: main ~46 -> ~36us. 41us harness fill floor.
//  r3: no-LDS direct-L2: 68.7us. Latency-bound serial chain.
//  r4: 2-phase staging: main ~35us (-1.5 only).
//  r5: class-sum identity; classsum v1 88us (LDS-atomic chain); p-dot
//      64/128 dims bug (+0.0625 bias) -> fixed r6.
//  r6: classsum v2 (uniform scan) still ~38us (serial uniform loads).
//  r7: classsum fused into convert as raw atomics: convert ~31us from
//      same-address contention. Main flat ~35us across r2/r4/r5 despite
//      epilogue diet + occupancy x2 -> NOT VALU/occupancy-bound ->
//      vmcnt(0)-drain structural stall (m233). This round: T4 counted
//      vmcnt in main + g replication in convert.

#define BB 8192
#define DD 128
#define NCLS 100
#define GREP 16              // class-sum replicas
#define NC 16                // column chunks (grid.x): 1024 blocks, 4/CU
#define COLCHUNK (BB / NC)   // 512 cols per WG
#define TILEC 64             // cols per staged tile (16KB)
#define ITERS (COLCHUNK / TILEC)
#define TEMP_INV 10.0f
#define MSHIFT 10.5f
#define C1F 14.426950408889634f    /* 10*log2(e)    */
#define C2F -15.148297929334116f   /* -10.5*log2(e) */

typedef __bf16 bf16x8 __attribute__((ext_vector_type(8)));
typedef float floatx4 __attribute__((ext_vector_type(4)));

__device__ inline float fast_exp2(float x) {
#if __has_builtin(__builtin_amdgcn_exp2f)
    return __builtin_amdgcn_exp2f(x);
#else
    return exp2f(x);
#endif
}

__device__ inline unsigned short f2bf(float f) {           // RTNE fp32->bf16
    unsigned u = __float_as_uint(f);
    return (unsigned short)((u + 0x7FFFu + ((u >> 16) & 1u)) >> 16);
}

__device__ inline float bf2f(unsigned short s) {
    return __uint_as_float(((unsigned)s) << 16);
}

__device__ inline void gload_lds16(const void* g, void* l) {
    __builtin_amdgcn_global_load_lds(
        (const __attribute__((address_space(1))) void*)g,
        (__attribute__((address_space(3))) void*)l, 16, 0, 0);
}

// ---- 1) canonicalize (+ detect + replicated class-sum atomics) ----
__global__ __launch_bounds__(256) void supcon_convert(
    const void* __restrict__ fin, const void* __restrict__ lin,
    unsigned short* __restrict__ fbf, int* __restrict__ lab,
    float* __restrict__ g)
{
    // Per-wave dtype detection: every wave reads the same 128-short feature
    // header and 128-int label header, butterfly-reduces across its own 64
    // lanes -> every thread holds the verdict, no LDS/sync needed.
    int lane = threadIdx.x & 63;
    unsigned ue = ((unsigned)((const unsigned short*)fin)[2 * lane]) << 16;
    float fe = __uint_as_float(ue);
    float ve = fe * fe;
    int odd_or = ((const int*)lin)[2 * lane + 1];
#pragma unroll
    for (int m = 1; m < 64; m <<= 1) {
        ve += __shfl_xor(ve, m, 64);
        odd_or |= __shfl_xor(odd_or, m, 64);
    }
    // true bf16 unit rows: sum sq of 64 even slots of row 0 is ~0.5.
    bool f_bf16 = (ve > 0.05f) && (ve < 4.0f);   // NaN-safe: NaN -> false
    bool l_i64  = (odd_or == 0);

    int gid = blockIdx.x * 256 + threadIdx.x;    // 262144 threads x 4 elements
    int row = gid >> 5;                          // 32 threads per 128-dim row
    int d0  = (gid & 31) * 4;

    const int* L = (const int*)lin;
    int c = l_i64 ? L[2 * row] : L[row];         // label of this thread's row

    float4 vf;                                   // bf16-rounded fp32 values
    if (!f_bf16) {
        float4 v = ((const float4*)fin)[gid];
        ushort4 o;
        o.x = f2bf(v.x); o.y = f2bf(v.y); o.z = f2bf(v.z); o.w = f2bf(v.w);
        ((ushort4*)fbf)[gid] = o;
        vf.x = bf2f(o.x); vf.y = bf2f(o.y); vf.z = bf2f(o.z); vf.w = bf2f(o.w);
    } else {
        ushort4 o = ((const ushort4*)fin)[gid];
        ((ushort4*)fbf)[gid] = o;
        vf.x = bf2f(o.x); vf.y = bf2f(o.y); vf.z = bf2f(o.z); vf.w = bf2f(o.w);
    }

    // Replicated class-sum: depth per address ~82/16 ~= 5.
    float* gc = g + (size_t)(blockIdx.x & (GREP - 1)) * (NCLS * DD) + c * DD + d0;
    atomicAdd(gc + 0, vf.x);
    atomicAdd(gc + 1, vf.y);
    atomicAdd(gc + 2, vf.z);
    atomicAdd(gc + 3, vf.w);

    if (blockIdx.x < 32) {
        int li = blockIdx.x * 256 + threadIdx.x;
        lab[li] = l_i64 ? L[2 * li] : L[li];
    }
}

// ---- 2) fold replicas: g[0][i] = sum_r g[r][i] ----
__global__ __launch_bounds__(256) void supcon_gmerge(float* __restrict__ g)
{
    int i = blockIdx.x * 256 + threadIdx.x;      // grid 50 -> 12800 threads
    float s = 0.f;
#pragma unroll
    for (int r = 0; r < GREP; ++r) s += g[(size_t)r * (NCLS * DD) + i];
    g[i] = s;
}

// Stage one 64-col B tile (16KB) into ldsB[bsel] via global_load_lds.
// LDS dest is LINEAR (wave-uniform base + lane*16, hardware rule); the XOR
// swizzle is applied to the SOURCE address. Dest slot d of row r receives
// source chunk d^(r&15); the swizzled ds_read of chunk k at slot k^(r&15)
// therefore returns chunk k — identical values to a swizzled ds_write path.
// 4 gload_lds per thread = 4 VMEM in flight per wave per stage.
#define STAGE_B(itx, bsel)                                                   \
    {                                                                        \
        const unsigned char* gB =                                            \
            Fbc + (size_t)(colchunkbase + (itx) * TILEC) * 256;              \
        unsigned char* lb = &ldsB[bsel][0];                                  \
        _Pragma("unroll")                                                    \
        for (int r = 0; r < 4; ++r) {                                        \
            int off = r * 4096 + tid * 16;                                   \
            int row = off >> 8;                                              \
            int gg  = (off >> 4) & 15;                                       \
            int gs  = gg ^ (row & 15);                                       \
            gload_lds16(gB + row * 256 + gs * 16, lb + off);                 \
        }                                                                    \
    }

// ---- 3) fused GEMM + exp partials (T4 counted-vmcnt pipeline) ----
__global__ __launch_bounds__(256, 2) void supcon_main(
    const unsigned short* __restrict__ Fb,
    float* __restrict__ e_part, float* __restrict__ diag)
{
    __shared__ unsigned char ldsB[2][16384];      // double-buffered 64-col tiles
    __shared__ float red[128][2];

    const int tid  = threadIdx.x;
    const int lane = tid & 63;
    const int wid  = tid >> 6;
    const int wrow = wid >> 1;
    const int wcol = wid & 1;
    const int quad = lane >> 4;
    const int l16  = lane & 15;

    const int chunk   = blockIdx.x;
    const int rowbase = blockIdx.y * 128;
    const int colchunkbase = chunk * COLCHUNK;

    const unsigned char* Fbc = (const unsigned char*)Fb;

    // Prologue: stage tile 0; A-frag loads (direct from L2) overlap it.
    STAGE_B(0, 0);

    bf16x8 afrag[4][4];
#pragma unroll
    for (int ti = 0; ti < 4; ++ti) {
        int row = rowbase + wrow * 64 + ti * 16 + l16;
        const unsigned char* gA = Fbc + (size_t)row * 256 + quad * 16;
#pragma unroll
        for (int k = 0; k < 4; ++k)
            afrag[ti][k] = *(const bf16x8*)(gA + k * 64);
    }

    float e_acc[16];
#pragma unroll
    for (int i = 0; i < 16; ++i) e_acc[i] = 0.0f;

    // Drain prologue (afrag + stage0) once; then never vmcnt(0) in-loop.
    asm volatile("s_waitcnt vmcnt(0)" ::: "memory");
    __builtin_amdgcn_s_barrier();
    __builtin_amdgcn_sched_barrier(0);

    int cur = 0;
    for (int it = 0; it < ITERS; ++it) {
        // Issue next tile's stage, then wait ONLY for the previous stage
        // (issued a full iteration ago -> wait is ~free). The just-issued
        // 4 loads stay in flight across the barrier and the whole compute.
        if (it + 1 < ITERS) {
            STAGE_B(it + 1, cur ^ 1);
            asm volatile("s_waitcnt vmcnt(4)" ::: "memory");
        } else {
            asm volatile("s_waitcnt vmcnt(0)" ::: "memory");
        }
        __builtin_amdgcn_s_barrier();     // buf[cur] fully landed for all waves
        __builtin_amdgcn_sched_barrier(0);

        int colbase = colchunkbase + it * TILEC;
        const unsigned char* lb = &ldsB[cur][0];

#pragma unroll
        for (int tj = 0; tj < 2; ++tj) {
            int coll = wcol * 32 + tj * 16 + l16;   // B[n=l16][k=quad*8+j]
            bf16x8 bfrag[4];
#pragma unroll
            for (int k = 0; k < 4; ++k) {
                int gg = k * 4 + quad;
                int gs = gg ^ (coll & 15);
                bfrag[k] = *(const bf16x8*)(lb + coll * 256 + gs * 16);
            }
            floatx4 acc[4];
#pragma unroll
            for (int ti = 0; ti < 4; ++ti) acc[ti] = (floatx4){0.f, 0.f, 0.f, 0.f};
#pragma unroll
            for (int k = 0; k < 4; ++k)
#pragma unroll
                for (int ti = 0; ti < 4; ++ti)
                    acc[ti] = __builtin_amdgcn_mfma_f32_16x16x32_bf16(
                        afrag[ti][k], bfrag[k], acc[ti], 0, 0, 0);

            // Diagonal capture: wave-uniform, rare (once per 64 diag cols).
            // Static indexing of acc (rule: no runtime ext_vector index).
            {
                int ctb = colbase + wcol * 32 + tj * 16;
                unsigned u = (unsigned)(ctb - (rowbase + wrow * 64));
                if (u < 64u) {
#pragma unroll
                    for (int ti2 = 0; ti2 < 4; ++ti2) {
                        if (u == (unsigned)(ti2 * 16)) {
#pragma unroll
                            for (int r = 0; r < 4; ++r)
                                if (l16 == quad * 4 + r)
                                    diag[ctb + l16] = acc[ti2][r];
                        }
                    }
                }
            }

#pragma unroll
            for (int ti = 0; ti < 4; ++ti) {
#pragma unroll
                for (int r = 0; r < 4; ++r) {
                    // C/D: D[row=quad*4+r][col=l16] (m89/m91 verified)
                    // 2 VALU + 1 trans per elem: fma, exp2, add.
                    float a = acc[ti][r];                        // raw dot
                    e_acc[ti * 4 + r] += fast_exp2(__builtin_fmaf(a, C1F, C2F));
                }
            }
        }

        // Separate this iter's LDS reads (all consumed by MFMA above, so
        // lgkmcnt already waited) from NEXT iter's stage overwriting
        // buf[cur^1]. Only needed while a future stage exists.
        if (it + 2 < ITERS) {
            __builtin_amdgcn_sched_barrier(0);
            __builtin_amdgcn_s_barrier();
        }
        cur ^= 1;
    }

    // reduce across 16 column-lanes (xor over lane bits 0..3)
#pragma unroll
    for (int i = 0; i < 16; ++i) {
        float e = e_acc[i];
#pragma unroll
        for (int m = 1; m < 16; m <<= 1) e += __shfl_xor(e, m, 64);
        if (l16 == 0) {
            int row_local = wrow * 64 + (i >> 2) * 16 + quad * 4 + (i & 3);
            red[row_local][wcol] = e;
        }
    }
    __syncthreads();

    if (tid < 128) {
        size_t idx = (size_t)chunk * BB + (rowbase + tid);
        e_part[idx] = red[tid][0] + red[tid][1];
    }
}

// ---- 4) e partials + p-dot -> scalar loss ----
__global__ __launch_bounds__(256) void supcon_reduce(
    const float* __restrict__ e_part, const unsigned short* __restrict__ Fb,
    const int* __restrict__ labels, const float* __restrict__ g,
    const float* __restrict__ diag,
    float* __restrict__ accbuf, float* __restrict__ out)
{
    // Exact per-class counts over the whole batch (labels in [0,100)).
    __shared__ int cnt[128];
    if (threadIdx.x < 128) cnt[threadIdx.x] = 0;
    __syncthreads();
    for (int i = threadIdx.x; i < BB; i += 256)
        atomicAdd(&cnt[labels[i]], 1);
    __syncthreads();

    int row = blockIdx.x * 256 + threadIdx.x;    // grid 32
    float e = 0.f;
#pragma unroll
    for (int c = 0; c < NC; ++c)
        e += e_part[(size_t)c * BB + row];

    int cls = labels[row];

    // p_i = a_i . g[lab_i]  (bf16-rounded features, fp32 merged class sums).
    const unsigned short* fr = Fb + (size_t)row * DD;
    const float* gr = g + cls * DD;
    float p0 = 0.f, p1 = 0.f;
#pragma unroll
    for (int q = 0; q < 16; ++q) {
        uint4  u  = ((const uint4*)fr)[q];        // 8 bf16
        float4 ga = ((const float4*)gr)[2 * q];
        float4 gb = ((const float4*)gr)[2 * q + 1];
        p0 = __builtin_fmaf(__uint_as_float(u.x << 16),          ga.x, p0);
        p1 = __builtin_fmaf(__uint_as_float(u.x & 0xFFFF0000u),  ga.y, p1);
        p0 = __builtin_fmaf(__uint_as_float(u.y << 16),          ga.z, p0);
        p1 = __builtin_fmaf(__uint_as_float(u.y & 0xFFFF0000u),  ga.w, p1);
        p0 = __builtin_fmaf(__uint_as_float(u.z << 16),          gb.x, p0);
        p1 = __builtin_fmaf(__uint_as_float(u.z & 0xFFFF0000u),  gb.y, p1);
        p0 = __builtin_fmaf(__uint_as_float(u.w << 16),          gb.z, p0);
        p1 = __builtin_fmaf(__uint_as_float(u.w & 0xFFFF0000u),  gb.w, p1);
    }
    float p = p0 + p1;

    // exact diagonal removal (e: same exp2 instruction on same input as main)
    float d = diag[row];
    e -= fast_exp2(__builtin_fmaf(d, C1F, C2F));
    p -= d;
    int n_i = cnt[cls] - 1;                      // integer-exact positive count

    float contrib = 0.f, vld = 0.f;
    if (n_i > 0) {
        vld = 1.0f;
        contrib = -(p * TEMP_INV / (float)n_i - MSHIFT - logf(e));
    }
#pragma unroll
    for (int m = 1; m < 64; m <<= 1) {
        contrib += __shfl_xor(contrib, m, 64);
        vld     += __shfl_xor(vld, m, 64);
    }
    __shared__ float rl[4], rv[4];
    int lane = threadIdx.x & 63, w = threadIdx.x >> 6;
    if (lane == 0) { rl[w] = contrib; rv[w] = vld; }
    __syncthreads();
    if (threadIdx.x == 0) {
        float L = rl[0] + rl[1] + rl[2] + rl[3];
        float V = rv[0] + rv[1] + rv[2] + rv[3];
        atomicAdd(&accbuf[0], L);
        atomicAdd(&accbuf[1], V);
        __threadfence();
        unsigned t = atomicAdd((unsigned*)accbuf + 2, 1u);
        if (t == 31u) {                      // last block: all adds fenced+done
            float Ls = atomicAdd(&accbuf[0], 0.0f);
            float Vs = atomicAdd(&accbuf[1], 0.0f);
            out[0] = (Vs > 0.5f) ? (Ls / Vs) : 0.0f;
        }
    }
}

extern "C" void kernel_launch(void* const* d_in, const int* in_sizes, int n_in,
                              void* d_out, int out_size, void* d_ws, size_t ws_size,
                              hipStream_t stream)
{
    const void* Fin = d_in[0];
    const void* Lin = d_in[1];

    // ws layout (~3.5 MB)
    unsigned short* fbf = (unsigned short*)d_ws;                          // 2 MB bf16 copy
    int*   lab      = (int*)((char*)d_ws + (size_t)BB * DD * 2);          // 32 KB
    float* e_part   = (float*)((char*)lab + (size_t)BB * 4);              // NC*B floats (512 KB)
    float* diag     = e_part + (size_t)NC * BB;                           // B floats
    float* g        = diag + BB;                                          // GREP x 100*128 floats
    float* accbuf   = g + (size_t)GREP * NCLS * DD;                       // 3 slots

    // Zero g replicas + accbuf (graph-capture legal, stream-ordered).
    hipMemsetAsync(g, 0, ((size_t)GREP * NCLS * DD + 3) * 4, stream);

    supcon_convert<<<BB * DD / 4 / 256, 256, 0, stream>>>(Fin, Lin, fbf, lab, g);

    supcon_gmerge<<<NCLS * DD / 256, 256, 0, stream>>>(g);

    dim3 grid(NC, BB / 128);
    supcon_main<<<grid, 256, 0, stream>>>(fbf, e_part, diag);

    supcon_reduce<<<32, 256, 0, stream>>>(e_part, fbf, lab, g, diag, accbuf, (float*)d_out);
}

// Round 9
// 135.657 us; speedup vs baseline: 1.0703x; 1.0703x over previous
//
#include <hip/hip_runtime.h>
#include <hip/hip_bf16.h>

// SupConLoss, B=8192, D=128, T=0.1. Output: single fp32 scalar.
//
// Pipeline (memset + 4 launches):
//   0) hipMemsetAsync  — zeroes 16 class-sum replicas + final accumulators.
//   1) supcon_convert  — dtype detection; features -> bf16 ws copy (RTNE),
//      labels -> int32; class sums into 16 REPLICAS of g (depth ~5/addr).
//   2) supcon_gmerge   — folds 16 replicas into g[0].
//   3) supcon_main     — fused bf16-MFMA GEMM (F.F^T) + exp accumulation.
//      NO LDS for B, NO barriers, NO inline asm: B fragments are register-
//      prefetched one full iteration ahead directly from L2 (T14 issue-
//      early/use-late; ~600cy compute covers ~300cy L2 latency). A kept in
//      registers. Double-state b0/b1 with manually 2x-unrolled body (static
//      names only — rule #20). Compiler inserts its own counted waitcnts.
//      LDS = 1KB red[] only.
//   4) supcon_reduce   — e partials + p_i = a_i.g[lab_i] dot -> loss.
//      n_i from exact label histogram. Diagonal removed exactly.
//      Last-block-atomic finalization (ticket zeroed by memset).
//
// Math: with ANY fixed shift M, per row i:
//   mean_log_prob_i = 10*p_i/n_i - M - log(sum_{j!=i} exp(s_ij - M))
// (shift cancels; M=10.5 >= max s_ij for unit-norm). exp folded to exp2.
//
// History:
//  r1: launch_bounds(256,4) -> VGPR=64 spill, 46->215us. Never clamp.
//  r2: NC=16 + n_acc removal: main ~46 -> ~36us. 41us harness fill floor.
//  r3: no-LDS direct-L2, NO prefetch: 68.7us. Serial load->use chain.
//  r4: 2-phase LDS staging: main ~35us. Not staging-latency-bound.
//  r5/r6: e-only epilogue + classsum identity: main still ~35us.
//      (flat 35 across r2/r4/r5 = LDS port ~5x oversubscribed vs MFMA
//      + barrier lockstep, not VALU/occupancy.)
//  r7: classsum fused as raw atomics: convert ~31us (same-addr depth 82).
//  r8: counted-vmcnt + sched_barrier(0) graft: REGALLOC SPILL — WRITE 2->
//      74MB, FETCH 8.4->45MB, main 51us, 144us cold (scratch first-touch).
//      Lesson: no sched fences in fat loops. This round: B via register
//      prefetch from L2, zero LDS-staging, zero barriers, zero asm.

#define BB 8192
#define DD 128
#define NCLS 100
#define GREP 16              // class-sum replicas
#define NC 8                 // column chunks (grid.x): 512 blocks
#define COLCHUNK (BB / NC)   // 1024 cols per WG
#define TILEC 64             // cols per iteration
#define ITERS (COLCHUNK / TILEC)   // 16 (even: 2x-unrolled loop)
#define TEMP_INV 10.0f
#define MSHIFT 10.5f
#define C1F 14.426950408889634f    /* 10*log2(e)    */
#define C2F -15.148297929334116f   /* -10.5*log2(e) */

typedef __bf16 bf16x8 __attribute__((ext_vector_type(8)));
typedef float floatx4 __attribute__((ext_vector_type(4)));

__device__ inline float fast_exp2(float x) {
#if __has_builtin(__builtin_amdgcn_exp2f)
    return __builtin_amdgcn_exp2f(x);
#else
    return exp2f(x);
#endif
}

__device__ inline unsigned short f2bf(float f) {           // RTNE fp32->bf16
    unsigned u = __float_as_uint(f);
    return (unsigned short)((u + 0x7FFFu + ((u >> 16) & 1u)) >> 16);
}

__device__ inline float bf2f(unsigned short s) {
    return __uint_as_float(((unsigned)s) << 16);
}

// ---- 1) canonicalize (+ detect + replicated class-sum atomics) ----
__global__ __launch_bounds__(256) void supcon_convert(
    const void* __restrict__ fin, const void* __restrict__ lin,
    unsigned short* __restrict__ fbf, int* __restrict__ lab,
    float* __restrict__ g)
{
    // Per-wave dtype detection: every wave reads the same 128-short feature
    // header and 128-int label header, butterfly-reduces across its own 64
    // lanes -> every thread holds the verdict, no LDS/sync needed.
    int lane = threadIdx.x & 63;
    unsigned ue = ((unsigned)((const unsigned short*)fin)[2 * lane]) << 16;
    float fe = __uint_as_float(ue);
    float ve = fe * fe;
    int odd_or = ((const int*)lin)[2 * lane + 1];
#pragma unroll
    for (int m = 1; m < 64; m <<= 1) {
        ve += __shfl_xor(ve, m, 64);
        odd_or |= __shfl_xor(odd_or, m, 64);
    }
    // true bf16 unit rows: sum sq of 64 even slots of row 0 is ~0.5.
    bool f_bf16 = (ve > 0.05f) && (ve < 4.0f);   // NaN-safe: NaN -> false
    bool l_i64  = (odd_or == 0);

    int gid = blockIdx.x * 256 + threadIdx.x;    // 262144 threads x 4 elements
    int row = gid >> 5;                          // 32 threads per 128-dim row
    int d0  = (gid & 31) * 4;

    const int* L = (const int*)lin;
    int c = l_i64 ? L[2 * row] : L[row];         // label of this thread's row

    float4 vf;                                   // bf16-rounded fp32 values
    if (!f_bf16) {
        float4 v = ((const float4*)fin)[gid];
        ushort4 o;
        o.x = f2bf(v.x); o.y = f2bf(v.y); o.z = f2bf(v.z); o.w = f2bf(v.w);
        ((ushort4*)fbf)[gid] = o;
        vf.x = bf2f(o.x); vf.y = bf2f(o.y); vf.z = bf2f(o.z); vf.w = bf2f(o.w);
    } else {
        ushort4 o = ((const ushort4*)fin)[gid];
        ((ushort4*)fbf)[gid] = o;
        vf.x = bf2f(o.x); vf.y = bf2f(o.y); vf.z = bf2f(o.z); vf.w = bf2f(o.w);
    }

    // Replicated class-sum: depth per address ~82/16 ~= 5.
    float* gc = g + (size_t)(blockIdx.x & (GREP - 1)) * (NCLS * DD) + c * DD + d0;
    atomicAdd(gc + 0, vf.x);
    atomicAdd(gc + 1, vf.y);
    atomicAdd(gc + 2, vf.z);
    atomicAdd(gc + 3, vf.w);

    if (blockIdx.x < 32) {
        int li = blockIdx.x * 256 + threadIdx.x;
        lab[li] = l_i64 ? L[2 * li] : L[li];
    }
}

// ---- 2) fold replicas: g[0][i] = sum_r g[r][i] ----
__global__ __launch_bounds__(256) void supcon_gmerge(float* __restrict__ g)
{
    int i = blockIdx.x * 256 + threadIdx.x;      // grid 50 -> 12800 threads
    float s = 0.f;
#pragma unroll
    for (int r = 0; r < GREP; ++r) s += g[(size_t)r * (NCLS * DD) + i];
    g[i] = s;
}

// Load the B fragments for 64-col tile `itx` into register set bb[2][4].
// Fully unrolled -> all indices compile-time (rule #20: registers, never
// scratch). Per instr: 64 lanes read 16 cols x 64B contiguous segments.
#define LOADB(bb, itx)                                                        \
    {                                                                         \
        _Pragma("unroll")                                                     \
        for (int tj = 0; tj < 2; ++tj) {                                      \
            int coll = colchunkbase + (itx) * TILEC + wcol * 32 + tj * 16 + l16; \
            const unsigned char* gB = Fbc + (size_t)coll * 256 + quad * 16;   \
            _Pragma("unroll")                                                 \
            for (int k = 0; k < 4; ++k)                                       \
                bb[tj][k] = *(const bf16x8*)(gB + k * 64);                    \
        }                                                                     \
    }

// Compute one 64-col tile from register set bb: 32 MFMA + diag + epilogue.
#define COMPUTE(bb, itx)                                                      \
    {                                                                         \
        int colbase = colchunkbase + (itx) * TILEC;                           \
        _Pragma("unroll")                                                     \
        for (int tj = 0; tj < 2; ++tj) {                                      \
            floatx4 acc[4];                                                   \
            _Pragma("unroll")                                                 \
            for (int ti = 0; ti < 4; ++ti) acc[ti] = (floatx4){0.f,0.f,0.f,0.f}; \
            _Pragma("unroll")                                                 \
            for (int k = 0; k < 4; ++k)                                       \
                _Pragma("unroll")                                             \
                for (int ti = 0; ti < 4; ++ti)                                \
                    acc[ti] = __builtin_amdgcn_mfma_f32_16x16x32_bf16(        \
                        afrag[ti][k], bb[tj][k], acc[ti], 0, 0, 0);           \
            /* Diagonal capture: wave-uniform, rare (1 per 64 diag cols). */  \
            {                                                                 \
                int ctb = colbase + wcol * 32 + tj * 16;                      \
                unsigned u = (unsigned)(ctb - (rowbase + wrow * 64));         \
                if (u < 64u) {                                                \
                    _Pragma("unroll")                                         \
                    for (int ti2 = 0; ti2 < 4; ++ti2) {                       \
                        if (u == (unsigned)(ti2 * 16)) {                      \
                            _Pragma("unroll")                                 \
                            for (int r = 0; r < 4; ++r)                       \
                                if (l16 == quad * 4 + r)                      \
                                    diag[ctb + l16] = acc[ti2][r];            \
                        }                                                     \
                    }                                                         \
                }                                                             \
            }                                                                 \
            _Pragma("unroll")                                                 \
            for (int ti = 0; ti < 4; ++ti) {                                  \
                _Pragma("unroll")                                             \
                for (int r = 0; r < 4; ++r) {                                 \
                    /* C/D: D[row=quad*4+r][col=l16]; fma+exp2+add */         \
                    float a = acc[ti][r];                                     \
                    e_acc[ti * 4 + r] += fast_exp2(__builtin_fmaf(a, C1F, C2F)); \
                }                                                             \
            }                                                                 \
        }                                                                     \
    }

// ---- 3) fused GEMM + exp partials (reg-prefetched B, barrier-free) ----
__global__ __launch_bounds__(256, 2) void supcon_main(
    const unsigned short* __restrict__ Fb,
    float* __restrict__ e_part, float* __restrict__ diag)
{
    __shared__ float red[128][2];                 // only LDS: cross-wave sum

    const int tid  = threadIdx.x;
    const int lane = tid & 63;
    const int wid  = tid >> 6;
    const int wrow = wid >> 1;
    const int wcol = wid & 1;
    const int quad = lane >> 4;
    const int l16  = lane & 15;

    const int chunk   = blockIdx.x;
    const int rowbase = blockIdx.y * 128;
    const int colchunkbase = chunk * COLCHUNK;

    const unsigned char* Fbc = (const unsigned char*)Fb;

    // A fragments direct from L2 (once per block).
    bf16x8 afrag[4][4];
#pragma unroll
    for (int ti = 0; ti < 4; ++ti) {
        int row = rowbase + wrow * 64 + ti * 16 + l16;
        const unsigned char* gA = Fbc + (size_t)row * 256 + quad * 16;
#pragma unroll
        for (int k = 0; k < 4; ++k)
            afrag[ti][k] = *(const bf16x8*)(gA + k * 64);
    }

    float e_acc[16];
#pragma unroll
    for (int i = 0; i < 16; ++i) e_acc[i] = 0.0f;

    // Double-state B registers, static names only.
    bf16x8 b0[2][4], b1[2][4];
    LOADB(b0, 0);

    for (int it = 0; it < ITERS; it += 2) {
        // Prefetch next tile FIRST (issue-early), compute current (use-late):
        // the compiler keeps the loads in flight across COMPUTE and waits
        // only at the next body's first use.
        LOADB(b1, it + 1);
        COMPUTE(b0, it);
        if (it + 2 < ITERS) LOADB(b0, it + 2);
        COMPUTE(b1, it + 1);
    }

    // reduce across 16 column-lanes (xor over lane bits 0..3)
#pragma unroll
    for (int i = 0; i < 16; ++i) {
        float e = e_acc[i];
#pragma unroll
        for (int m = 1; m < 16; m <<= 1) e += __shfl_xor(e, m, 64);
        if (l16 == 0) {
            int row_local = wrow * 64 + (i >> 2) * 16 + quad * 4 + (i & 3);
            red[row_local][wcol] = e;
        }
    }
    __syncthreads();

    if (tid < 128) {
        size_t idx = (size_t)chunk * BB + (rowbase + tid);
        e_part[idx] = red[tid][0] + red[tid][1];
    }
}

// ---- 4) e partials + p-dot -> scalar loss ----
__global__ __launch_bounds__(256) void supcon_reduce(
    const float* __restrict__ e_part, const unsigned short* __restrict__ Fb,
    const int* __restrict__ labels, const float* __restrict__ g,
    const float* __restrict__ diag,
    float* __restrict__ accbuf, float* __restrict__ out)
{
    // Exact per-class counts over the whole batch (labels in [0,100)).
    __shared__ int cnt[128];
    if (threadIdx.x < 128) cnt[threadIdx.x] = 0;
    __syncthreads();
    for (int i = threadIdx.x; i < BB; i += 256)
        atomicAdd(&cnt[labels[i]], 1);
    __syncthreads();

    int row = blockIdx.x * 256 + threadIdx.x;    // grid 32
    float e = 0.f;
#pragma unroll
    for (int c = 0; c < NC; ++c)
        e += e_part[(size_t)c * BB + row];

    int cls = labels[row];

    // p_i = a_i . g[lab_i]  (bf16-rounded features, fp32 merged class sums).
    const unsigned short* fr = Fb + (size_t)row * DD;
    const float* gr = g + cls * DD;
    float p0 = 0.f, p1 = 0.f;
#pragma unroll
    for (int q = 0; q < 16; ++q) {
        uint4  u  = ((const uint4*)fr)[q];        // 8 bf16
        float4 ga = ((const float4*)gr)[2 * q];
        float4 gb = ((const float4*)gr)[2 * q + 1];
        p0 = __builtin_fmaf(__uint_as_float(u.x << 16),          ga.x, p0);
        p1 = __builtin_fmaf(__uint_as_float(u.x & 0xFFFF0000u),  ga.y, p1);
        p0 = __builtin_fmaf(__uint_as_float(u.y << 16),          ga.z, p0);
        p1 = __builtin_fmaf(__uint_as_float(u.y & 0xFFFF0000u),  ga.w, p1);
        p0 = __builtin_fmaf(__uint_as_float(u.z << 16),          gb.x, p0);
        p1 = __builtin_fmaf(__uint_as_float(u.z & 0xFFFF0000u),  gb.y, p1);
        p0 = __builtin_fmaf(__uint_as_float(u.w << 16),          gb.z, p0);
        p1 = __builtin_fmaf(__uint_as_float(u.w & 0xFFFF0000u),  gb.w, p1);
    }
    float p = p0 + p1;

    // exact diagonal removal (e: same exp2 instruction on same input as main)
    float d = diag[row];
    e -= fast_exp2(__builtin_fmaf(d, C1F, C2F));
    p -= d;
    int n_i = cnt[cls] - 1;                      // integer-exact positive count

    float contrib = 0.f, vld = 0.f;
    if (n_i > 0) {
        vld = 1.0f;
        contrib = -(p * TEMP_INV / (float)n_i - MSHIFT - logf(e));
    }
#pragma unroll
    for (int m = 1; m < 64; m <<= 1) {
        contrib += __shfl_xor(contrib, m, 64);
        vld     += __shfl_xor(vld, m, 64);
    }
    __shared__ float rl[4], rv[4];
    int lane = threadIdx.x & 63, w = threadIdx.x >> 6;
    if (lane == 0) { rl[w] = contrib; rv[w] = vld; }
    __syncthreads();
    if (threadIdx.x == 0) {
        float L = rl[0] + rl[1] + rl[2] + rl[3];
        float V = rv[0] + rv[1] + rv[2] + rv[3];
        atomicAdd(&accbuf[0], L);
        atomicAdd(&accbuf[1], V);
        __threadfence();
        unsigned t = atomicAdd((unsigned*)accbuf + 2, 1u);
        if (t == 31u) {                      // last block: all adds fenced+done
            float Ls = atomicAdd(&accbuf[0], 0.0f);
            float Vs = atomicAdd(&accbuf[1], 0.0f);
            out[0] = (Vs > 0.5f) ? (Ls / Vs) : 0.0f;
        }
    }
}

extern "C" void kernel_launch(void* const* d_in, const int* in_sizes, int n_in,
                              void* d_out, int out_size, void* d_ws, size_t ws_size,
                              hipStream_t stream)
{
    const void* Fin = d_in[0];
    const void* Lin = d_in[1];

    // ws layout (~3.2 MB)
    unsigned short* fbf = (unsigned short*)d_ws;                          // 2 MB bf16 copy
    int*   lab      = (int*)((char*)d_ws + (size_t)BB * DD * 2);          // 32 KB
    float* e_part   = (float*)((char*)lab + (size_t)BB * 4);              // NC*B floats (256 KB)
    float* diag     = e_part + (size_t)NC * BB;                           // B floats
    float* g        = diag + BB;                                          // GREP x 100*128 floats
    float* accbuf   = g + (size_t)GREP * NCLS * DD;                       // 3 slots

    // Zero g replicas + accbuf (graph-capture legal, stream-ordered).
    hipMemsetAsync(g, 0, ((size_t)GREP * NCLS * DD + 3) * 4, stream);

    supcon_convert<<<BB * DD / 4 / 256, 256, 0, stream>>>(Fin, Lin, fbf, lab, g);

    supcon_gmerge<<<NCLS * DD / 256, 256, 0, stream>>>(g);

    dim3 grid(NC, BB / 128);
    supcon_main<<<grid, 256, 0, stream>>>(fbf, e_part, diag);

    supcon_reduce<<<32, 256, 0, stream>>>(e_part, fbf, lab, g, diag, accbuf, (float*)d_out);
}